// Round 6
// baseline (253.710 us; speedup 1.0000x reference)
//
#include <hip/hip_runtime.h>
#include <hip/hip_bf16.h>
#include <math.h>

// Problem constants
#define NB 16          // batch
#define NS 4           // seq (new tokens)
#define NN 2048        // model dim
#define ND 128         // head dim
#define NH 16          // heads
#define NM 4096        // cache length
#define NCHK2 32       // M-chunks for split attention (128 rows each)
#define CHROWS2 128    // rows per chunk
#define NUNITS 64      // 2-row units per chunk
#define NKC 16         // k-chunks for QKV split-k

// Workspace layout (float offsets)
#define SC_OFF   0u           // [64] rmsnorm scales
#define Q_OFF    131072u      // [64][2048]
#define K_OFF    262144u      // [64][2048] new K rows
#define V_OFF    393216u      // [64][2048] new V rows
#define OP_OFF   524288u      // [256 bh][32 ch][4 q][128 d] partial O (16.8MB)
#define ML_OFF   4718592u     // [256 bh][32 ch][4 q][2] (max, sumexp)
#define PART_OFF 4784128u     // [16 kc][3 which][64][2048] QKV partials (25MB)

// ------------------------------------------------- RMSNorm scales only
__global__ __launch_bounds__(256) void k_rmsnorm(const float* __restrict__ X,
                                                 float* __restrict__ ws) {
    const int row = blockIdx.x;        // 0..63
    const int tid = threadIdx.x;
    const float* xr = X + (size_t)row * NN;
    float4 a = *(const float4*)(xr + tid * 4);
    float4 b = *(const float4*)(xr + 1024 + tid * 4);
    float ss = a.x*a.x + a.y*a.y + a.z*a.z + a.w*a.w
             + b.x*b.x + b.y*b.y + b.z*b.z + b.w*b.w;
    #pragma unroll
    for (int off = 32; off; off >>= 1) ss += __shfl_xor(ss, off);
    __shared__ float ls[4];
    if ((tid & 63) == 0) ls[tid >> 6] = ss;
    __syncthreads();
    if (tid == 0)
        ws[SC_OFF + row] = rsqrtf((ls[0] + ls[1] + ls[2] + ls[3]) * (1.0f / NN));
}

// -------------------------------------------- QKV projection (tiled f32 GEMM)
// grid (16 col-tiles of 128, 3 which, 16 k-chunks of 128). block 256.
__global__ __launch_bounds__(256) void k_qkv(const float* __restrict__ X,
                                             const float* __restrict__ Wq,
                                             const float* __restrict__ Wk,
                                             const float* __restrict__ Wv,
                                             float* __restrict__ ws) {
    __shared__ float xsT[64][68];    // [kk][row] (+pad)
    __shared__ float wt[64][132];    // [kk][col] (+pad)
    const int ct    = blockIdx.x;    // col tile (128 cols)
    const int which = blockIdx.y;    // 0..2
    const int kc    = blockIdx.z;    // 0..15
    const float* __restrict__ W = (which == 0) ? Wq : (which == 1) ? Wk : Wv;
    const int tid = threadIdx.x;
    const int c0  = ct * 128;
    const int rg  = tid >> 5;        // 0..7 (8 rows each)
    const int cg  = tid & 31;        // 0..31 (4 cols each)
    const float scl = ws[SC_OFF + (tid >> 2)];   // scale for staged row

    float4 acc[8];
    #pragma unroll
    for (int i = 0; i < 8; i++) acc[i] = make_float4(0.f, 0.f, 0.f, 0.f);

    for (int s = 0; s < 2; s++) {
        const int k0 = kc * 128 + s * 64;
        __syncthreads();
        // stage Xn 64x64 transposed (scale applied)
        {
            const int r  = tid >> 2;
            const int q4 = tid & 3;
            #pragma unroll
            for (int i = 0; i < 4; i++) {
                const int f4 = q4 + i * 4;                 // 0..15
                float4 v = *(const float4*)(X + (size_t)r * NN + k0 + f4 * 4);
                xsT[f4 * 4 + 0][r] = v.x * scl;
                xsT[f4 * 4 + 1][r] = v.y * scl;
                xsT[f4 * 4 + 2][r] = v.z * scl;
                xsT[f4 * 4 + 3][r] = v.w * scl;
            }
        }
        // stage W 64x128: per iter 8 rows x 512B contiguous
        {
            #pragma unroll
            for (int j8 = 0; j8 < 8; j8++) {
                const int kk  = j8 * 8 + (tid >> 5);
                const int f4c = tid & 31;
                float4 v = *(const float4*)(W + (size_t)(k0 + kk) * NN + c0 + f4c * 4);
                *(float4*)&wt[kk][f4c * 4] = v;
            }
        }
        __syncthreads();
        #pragma unroll 8
        for (int kk = 0; kk < 64; kk++) {
            const float4 x0 = *(const float4*)&xsT[kk][rg * 8];
            const float4 x1 = *(const float4*)&xsT[kk][rg * 8 + 4];
            const float4 w4 = *(const float4*)&wt[kk][cg * 4];
            acc[0].x += x0.x*w4.x; acc[0].y += x0.x*w4.y; acc[0].z += x0.x*w4.z; acc[0].w += x0.x*w4.w;
            acc[1].x += x0.y*w4.x; acc[1].y += x0.y*w4.y; acc[1].z += x0.y*w4.z; acc[1].w += x0.y*w4.w;
            acc[2].x += x0.z*w4.x; acc[2].y += x0.z*w4.y; acc[2].z += x0.z*w4.z; acc[2].w += x0.z*w4.w;
            acc[3].x += x0.w*w4.x; acc[3].y += x0.w*w4.y; acc[3].z += x0.w*w4.z; acc[3].w += x0.w*w4.w;
            acc[4].x += x1.x*w4.x; acc[4].y += x1.x*w4.y; acc[4].z += x1.x*w4.z; acc[4].w += x1.x*w4.w;
            acc[5].x += x1.y*w4.x; acc[5].y += x1.y*w4.y; acc[5].z += x1.y*w4.z; acc[5].w += x1.y*w4.w;
            acc[6].x += x1.z*w4.x; acc[6].y += x1.z*w4.y; acc[6].z += x1.z*w4.z; acc[6].w += x1.z*w4.w;
            acc[7].x += x1.w*w4.x; acc[7].y += x1.w*w4.y; acc[7].z += x1.w*w4.z; acc[7].w += x1.w*w4.w;
        }
    }
    float* po = ws + PART_OFF + (size_t)(kc * 3 + which) * 131072u;
    #pragma unroll
    for (int i = 0; i < 8; i++)
        *(float4*)(po + (size_t)(rg * 8 + i) * NN + c0 + cg * 4) = acc[i];
}

// ------------------------------------------ sum the 16 k-chunk partials
__global__ __launch_bounds__(256) void k_reduce(float* __restrict__ ws) {
    const int idx = blockIdx.x * 256 + threadIdx.x;    // f4 index, 98304 total
    const int which = idx >> 15;                       // /32768
    const int off   = idx & 32767;                     // f4 within [64][2048]
    float4 s = make_float4(0.f, 0.f, 0.f, 0.f);
    #pragma unroll
    for (int kcc = 0; kcc < NKC; kcc++) {
        const float4 v = *(const float4*)(ws + PART_OFF
                         + (size_t)(kcc * 3 + which) * 131072u + (size_t)off * 4);
        s.x += v.x; s.y += v.y; s.z += v.z; s.w += v.w;
    }
    *(float4*)(ws + Q_OFF + (size_t)which * 131072u + (size_t)off * 4) = s;
}

// ------------------------------- wave-autonomous streaming flash attention
// grid (32 ch, 16 h, 16 b), block 64 = ONE wave. 128 rows per block, streamed
// as 64 two-row units through a 4-slot LDS ring (8KB) via global_load_lds.
// Counted vmcnt(6) keeps 6KB in flight per wave at all times; NO barriers.
// Lane = (q = lane>>4, sub = lane&15). Scores: lane dots d-segments
// [sub*4,+4) and [64+sub*4,+4); 8-lane-group shfl reduce. m/l identical
// within q-group -> no end reduction. O: lane owns same d-segments.
__global__ __launch_bounds__(64, 4) void k_attn(const float* __restrict__ cK,
                                                const float* __restrict__ cV,
                                                const int* __restrict__ Pp,
                                                float* __restrict__ ws) {
    const int ch = blockIdx.x, h = blockIdx.y, b = blockIdx.z;
    const int lane = threadIdx.x;
    const int q = lane >> 4, sub = lane & 15;
    const int P = *Pp;
    __shared__ float ring[4][2][256];   // [slot][K/V][2 rows x 128]

    const float* kbase = cK + (size_t)(b * NH + h) * NM * ND;
    const float* vbase = cV + (size_t)(b * NH + h) * NM * ND;
    const float* knew  = ws + K_OFF;
    const float* vnew  = ws + V_OFF;
    const int mb0 = ch * CHROWS2;

    // Q fragments for this lane (8 floats)
    const float* qrow = ws + Q_OFF + (size_t)(b * 4 + q) * NN + h * 128;
    const float4 qA = *(const float4*)(qrow + sub * 4);
    const float4 qB = *(const float4*)(qrow + 64 + sub * 4);

    auto STAGE = [&](int u, int slot) {
        const int row = mb0 + u * 2 + (lane >> 5);
        const int c = (lane & 31) * 4;
        const float* ksrc; const float* vsrc;
        if (row >= P && row < P + NS) {
            const size_t ro = (size_t)(b * 4 + (row - P)) * NN + h * 128 + c;
            ksrc = knew + ro; vsrc = vnew + ro;
        } else {
            const size_t ro = (size_t)row * ND + c;
            ksrc = kbase + ro; vsrc = vbase + ro;
        }
        __builtin_amdgcn_global_load_lds(
            (const __attribute__((address_space(1))) void*)ksrc,
            (__attribute__((address_space(3))) void*)(&ring[slot][0][0]),
            16, 0, 0);
        __builtin_amdgcn_global_load_lds(
            (const __attribute__((address_space(1))) void*)vsrc,
            (__attribute__((address_space(3))) void*)(&ring[slot][1][0]),
            16, 0, 0);
    };

    float m_run = -INFINITY, l_run = 0.f;
    float o0=0.f,o1=0.f,o2=0.f,o3=0.f,o4=0.f,o5=0.f,o6=0.f,o7=0.f;

    auto PROCESS = [&](int slot) {
        const float* kp = &ring[slot][0][0];
        const float* vp = &ring[slot][1][0];
        const float4 k00 = *(const float4*)&kp[sub * 4];
        const float4 k01 = *(const float4*)&kp[64 + sub * 4];
        const float4 k10 = *(const float4*)&kp[128 + sub * 4];
        const float4 k11 = *(const float4*)&kp[192 + sub * 4];
        float s0 = k00.x*qA.x + k00.y*qA.y + k00.z*qA.z + k00.w*qA.w
                 + k01.x*qB.x + k01.y*qB.y + k01.z*qB.z + k01.w*qB.w;
        float s1 = k10.x*qA.x + k10.y*qA.y + k10.z*qA.z + k10.w*qA.w
                 + k11.x*qB.x + k11.y*qB.y + k11.z*qB.z + k11.w*qB.w;
        #pragma unroll
        for (int off = 1; off <= 8; off <<= 1) {
            s0 += __shfl_xor(s0, off);
            s1 += __shfl_xor(s1, off);
        }
        const float wm = fmaxf(s0, s1);
        if (wm > m_run) {                         // rare (log-many) rescale
            const float fac = __expf(m_run - wm);
            l_run *= fac;
            o0*=fac; o1*=fac; o2*=fac; o3*=fac;
            o4*=fac; o5*=fac; o6*=fac; o7*=fac;
            m_run = wm;
        }
        const float p0 = __expf(s0 - m_run);
        const float p1 = __expf(s1 - m_run);
        l_run += p0 + p1;
        const float4 v00 = *(const float4*)&vp[sub * 4];
        const float4 v01 = *(const float4*)&vp[64 + sub * 4];
        const float4 v10 = *(const float4*)&vp[128 + sub * 4];
        const float4 v11 = *(const float4*)&vp[192 + sub * 4];
        o0 += p0*v00.x + p1*v10.x;  o1 += p0*v00.y + p1*v10.y;
        o2 += p0*v00.z + p1*v10.z;  o3 += p0*v00.w + p1*v10.w;
        o4 += p0*v01.x + p1*v11.x;  o5 += p0*v01.y + p1*v11.y;
        o6 += p0*v01.z + p1*v11.z;  o7 += p0*v01.w + p1*v11.w;
    };

    STAGE(0, 0); STAGE(1, 1); STAGE(2, 2);
    for (int u = 0; u < NUNITS - 3; ++u) {
        STAGE(u + 3, (u + 3) & 3);
        __builtin_amdgcn_sched_barrier(0);
        asm volatile("s_waitcnt vmcnt(6)" ::: "memory");   // unit u ready
        __builtin_amdgcn_sched_barrier(0);
        PROCESS(u & 3);
    }
    asm volatile("s_waitcnt vmcnt(4)" ::: "memory");
    __builtin_amdgcn_sched_barrier(0);
    PROCESS((NUNITS - 3) & 3);
    asm volatile("s_waitcnt vmcnt(2)" ::: "memory");
    __builtin_amdgcn_sched_barrier(0);
    PROCESS((NUNITS - 2) & 3);
    asm volatile("s_waitcnt vmcnt(0)" ::: "memory");
    __builtin_amdgcn_sched_barrier(0);
    PROCESS((NUNITS - 1) & 3);

    // write partials (m/l identical within q-group; no reduction needed)
    const size_t base = (((size_t)(b * NH + h) * NCHK2 + ch) * 4 + q);
    float* op = ws + OP_OFF + base * 128;
    *(float4*)(op + sub * 4)      = make_float4(o0, o1, o2, o3);
    *(float4*)(op + 64 + sub * 4) = make_float4(o4, o5, o6, o7);
    if (sub == 0) {
        ws[ML_OFF + base * 2]     = m_run;
        ws[ML_OFF + base * 2 + 1] = l_run;
    }
}

// --------------------------------------------- final combine over chunks
__global__ __launch_bounds__(256) void k_comb(const float* __restrict__ ws,
                                              float* __restrict__ out) {
    const int bh = blockIdx.x;           // 0..255
    const int b = bh >> 4, h = bh & 15;
    const int tid = threadIdx.x;
    const int q = tid >> 6, d0 = (tid & 63) * 2;
    float ms = -INFINITY;
    #pragma unroll
    for (int c = 0; c < NCHK2; c++)
        ms = fmaxf(ms, ws[ML_OFF + (((size_t)bh * NCHK2 + c) * 4 + q) * 2]);
    float o0 = 0.f, o1 = 0.f, den = 0.f;
    #pragma unroll 8
    for (int c = 0; c < NCHK2; c++) {
        const size_t mi = (((size_t)bh * NCHK2 + c) * 4 + q) * 2;
        float e = __expf(ws[ML_OFF + mi] - ms);
        den += e * ws[ML_OFF + mi + 1];
        const size_t pi = (((size_t)bh * NCHK2 + c) * 4 + q) * 128 + d0;
        o0 += e * ws[OP_OFF + pi];
        o1 += e * ws[OP_OFF + pi + 1];
    }
    const float inv = 1.0f / den;
    const size_t oi = (size_t)(b * 4 + q) * NN + h * 128 + d0;
    *(float2*)(out + oi) = make_float2(o0 * inv, o1 * inv);
}

// ----------------------------------------------------------------- launch
extern "C" void kernel_launch(void* const* d_in, const int* in_sizes, int n_in,
                              void* d_out, int out_size, void* d_ws, size_t ws_size,
                              hipStream_t stream) {
    const float* X  = (const float*)d_in[0];
    const float* Wq = (const float*)d_in[1];
    const float* Wk = (const float*)d_in[2];
    const float* Wv = (const float*)d_in[3];
    const float* cK = (const float*)d_in[4];
    const float* cV = (const float*)d_in[5];
    const int*   Pp = (const int*)d_in[6];
    float* ws = (float*)d_ws;
    float* out = (float*)d_out;

    hipLaunchKernelGGL(k_rmsnorm, dim3(64), dim3(256), 0, stream, X, ws);
    hipLaunchKernelGGL(k_qkv, dim3(16, 3, NKC), dim3(256), 0, stream, X, Wq, Wk, Wv, ws);
    hipLaunchKernelGGL(k_reduce, dim3(384), dim3(256), 0, stream, ws);
    hipLaunchKernelGGL(k_attn, dim3(NCHK2, NH, NB), dim3(64), 0, stream, cK, cV, Pp, ws);
    hipLaunchKernelGGL(k_comb, dim3(NB * NH), dim3(256), 0, stream, ws, out);
}